// Round 7
// baseline (187.613 us; speedup 1.0000x reference)
//
#include <hip/hip_runtime.h>
#include <hip/hip_bf16.h>
#include <hip/hip_fp8.h>

typedef float f32x4 __attribute__((ext_vector_type(4)));
typedef long long i64;

#define N_SPK 1024
#define M_UTT 40
#define D_FEAT 768
#define NROWS (N_SPK * M_UTT)
#define LOG2E 1.44269504088896340736f
#define LN2   0.69314718055994530942f

#define BM 128
#define BN 128
#define BKB 64             // fp8 elems (=bytes) per K-tile
#define KT (D_FEAT / BKB)  // 12
#define ROWB 768           // bytes per fp8 source row

// xn stored *8, cc stored *8  ->  acc = 64 * sim
#define INV_SS (1.0f / 64.0f)
#define SCL 8.0f

__device__ __forceinline__ unsigned char to_fp8(float v) {
  __hip_fp8_e4m3 t(v);
  return (unsigned char)t.__x;
}

// ---------------- Kernel 1: fused L2-normalize + inclusive centroid (fp8 out, x8) ----------------
__global__ __launch_bounds__(256) void k_norm_cent(const float* __restrict__ x,
                                                   unsigned char* __restrict__ xn,
                                                   unsigned char* __restrict__ cc) {
  const int n = blockIdx.x, t = threadIdx.x;
  const float* xb = x + (size_t)n * (M_UTT * D_FEAT);
  unsigned char* ob = xn + (size_t)n * (M_UTT * D_FEAT);
  const int lane = t & 63, wv = t >> 6;
  __shared__ float wsum[2][2][4];  // [parity][row-in-pair][wave]
  float c0 = 0.f, c1 = 0.f, c2 = 0.f;
  for (int m = 0; m < M_UTT; m += 2) {
    const int p = (m >> 1) & 1;
    const float* r0 = xb + (size_t)m * D_FEAT;
    const float* r1 = r0 + D_FEAT;
    float a0 = r0[t], a1 = r0[t + 256], a2 = r0[t + 512];
    float b0 = r1[t], b1 = r1[t + 256], b2 = r1[t + 512];
    float s0 = a0 * a0 + a1 * a1 + a2 * a2;
    float s1 = b0 * b0 + b1 * b1 + b2 * b2;
#pragma unroll
    for (int d = 1; d < 64; d <<= 1) {
      s0 += __shfl_xor(s0, d, 64);
      s1 += __shfl_xor(s1, d, 64);
    }
    if (lane == 0) { wsum[p][0][wv] = s0; wsum[p][1][wv] = s1; }
    __syncthreads();  // parity double-buffer: slot p reused 2 barriers later -> safe
    const float t0 = wsum[p][0][0] + wsum[p][0][1] + wsum[p][0][2] + wsum[p][0][3];
    const float t1 = wsum[p][1][0] + wsum[p][1][1] + wsum[p][1][2] + wsum[p][1][3];
    const float i0 = 1.0f / fmaxf(sqrtf(t0), 1e-12f);
    const float i1 = 1.0f / fmaxf(sqrtf(t1), 1e-12f);
    a0 *= i0; a1 *= i0; a2 *= i0;
    b0 *= i1; b1 *= i1; b2 *= i1;
    unsigned char* o0 = ob + (size_t)m * D_FEAT;
    unsigned char* o1 = o0 + D_FEAT;
    o0[t] = to_fp8(a0 * SCL); o0[t + 256] = to_fp8(a1 * SCL); o0[t + 512] = to_fp8(a2 * SCL);
    o1[t] = to_fp8(b0 * SCL); o1[t + 256] = to_fp8(b1 * SCL); o1[t + 512] = to_fp8(b2 * SCL);
    c0 += a0 + b0; c1 += a1 + b1; c2 += a2 + b2;
  }
  unsigned char* co = cc + (size_t)n * D_FEAT;
  co[t]       = to_fp8(c0 * (SCL / M_UTT));
  co[t + 256] = to_fp8(c1 * (SCL / M_UTT));
  co[t + 512] = to_fp8(c2 * (SCL / M_UTT));
}

// ---------------- Kernel 2: 128x128 fp8 GEMM, K=64/tile, 5 blocks/CU, counted vmcnt ----------------
// 256 thr = 4 waves (2x2 of 64x64; 4x4 frags of 16x16x32 fp8; 32 MFMA per K-tile).
// LDS 32KB dbuf (16KB/tile): each 64B src row pair-packed into 128B LDS rows,
// XOR swizzle on bits 4-6 (physical_inner = logical_inner ^ ((R&7)<<4); bit6 = row parity).
// Loop: stage k+1 -> vmcnt(4) -> barrier -> 16x ds_read_b64 + 32 MFMA -> lgkmcnt(0) -> barrier.
#define GLD(g, l) __builtin_amdgcn_global_load_lds( \
    (const __attribute__((address_space(1))) unsigned int*)(g), \
    (__attribute__((address_space(3))) unsigned int*)(l), 16, 0, 0)

__global__ __launch_bounds__(256, 5) void k_gemm_part(
    const unsigned char* __restrict__ XN, const unsigned char* __restrict__ CC,
    const float* __restrict__ wp, const float* __restrict__ bp,
    float2* __restrict__ ppart, float* __restrict__ picked2) {

  __shared__ __align__(16) char smem[32768];

  const int tid  = threadIdx.x;
  const int wave = tid >> 6, lane = tid & 63;
  const int l16  = lane & 15, lg = lane >> 4;
  const int wr   = wave >> 1, wc = wave & 1;

  // XCD swizzle: 2560 = 8 XCD x 320; a row-tile's 8 col-blocks share one XCD's L2
  const int bid = blockIdx.x;
  const int xcd = bid & 7;
  const int tt  = bid >> 3;              // 0..319
  const int rb  = xcd * 40 + (tt >> 3);  // 0..319
  const int cb  = tt & 7;                // 0..7
  const int rowbase = rb * BM;
  const int colbase = cb * BN;

  // staging source mapping (inverse of pair-packed swizzle):
  // thread t fills LDS bytes o = chunk*4096 + t*16; LDS-row R = o>>7,
  // logical_inner = (o&127) ^ ((R&7)<<4); src_row = 2R + (li>>6), src k-byte = li&63.
  const int R7   = (tid >> 3) & 7;
  const int li   = ((tid & 7) * 16) ^ (R7 << 4);
  const int row0 = 2 * (tid >> 3) + (li >> 6);   // 0..63
  const int kb   = li & 63;
  const int t16  = tid * 16;
  const unsigned char* gA = XN + (size_t)(rowbase + row0) * ROWB + kb;
  const unsigned char* gB = CC + (size_t)(colbase + row0) * ROWB + kb;

  // fragment ds_read_b64 offsets (substep 0; substep 1 = ^32):
  // src row r = band*64 + i*16 + l16 -> LDS-row R = band*32 + i*8 + (l16>>1);
  // logical inner = (parity<<6)|(s<<5)|(lg<<3), physical = logical ^ ((R&7)<<4)
  const int xr  = ((l16 >> 1) & 7) << 4;
  const int in0 = ((((l16 & 1) << 6) | (lg << 3)) ^ xr);
  int aoff[4], boff[4];
#pragma unroll
  for (int i = 0; i < 4; ++i) {
    aoff[i] = (wr * 32 + i * 8 + (l16 >> 1)) * 128 + in0;
    boff[i] = 8192 + (wc * 32 + i * 8 + (l16 >> 1)) * 128 + in0;
  }

  f32x4 acc[4][4];
#pragma unroll
  for (int i = 0; i < 4; ++i)
#pragma unroll
    for (int j = 0; j < 4; ++j) acc[i][j] = (f32x4){0.f, 0.f, 0.f, 0.f};

  auto STAGE = [&](int buf, int koff) {
    char* sb = smem + buf * 16384;
    GLD(gA + koff,              sb + t16);
    GLD(gA + 64 * ROWB + koff,  sb + 4096 + t16);
    GLD(gB + koff,              sb + 8192 + t16);
    GLD(gB + 64 * ROWB + koff,  sb + 12288 + t16);
  };

  STAGE(0, 0);  // prologue: tile 0

  for (int k = 0; k < KT; ++k) {
    const char* bb = smem + (k & 1) * 16384;
    if (k + 1 < KT) {
      STAGE((k + 1) & 1, (k + 1) * BKB);
      asm volatile("s_waitcnt vmcnt(4)" ::: "memory");  // tile k landed; k+1 in flight
    } else {
      asm volatile("s_waitcnt vmcnt(0)" ::: "memory");
    }
    __builtin_amdgcn_s_barrier();

    i64 av0[4], av1[4], bv0[4], bv1[4];
#pragma unroll
    for (int i = 0; i < 4; ++i) {
      av0[i] = *(const i64*)(bb + aoff[i]);
      av1[i] = *(const i64*)(bb + (aoff[i] ^ 32));
    }
#pragma unroll
    for (int j = 0; j < 4; ++j) {
      bv0[j] = *(const i64*)(bb + boff[j]);
      bv1[j] = *(const i64*)(bb + (boff[j] ^ 32));
    }
    __builtin_amdgcn_s_setprio(1);
#pragma unroll
    for (int i = 0; i < 4; ++i)
#pragma unroll
      for (int j = 0; j < 4; ++j)
        acc[i][j] = __builtin_amdgcn_mfma_f32_16x16x32_fp8_fp8(av0[i], bv0[j], acc[i][j], 0, 0, 0);
#pragma unroll
    for (int i = 0; i < 4; ++i)
#pragma unroll
      for (int j = 0; j < 4; ++j)
        acc[i][j] = __builtin_amdgcn_mfma_f32_16x16x32_fp8_fp8(av1[i], bv1[j], acc[i][j], 0, 0, 0);
    __builtin_amdgcn_s_setprio(0);
    asm volatile("s_waitcnt lgkmcnt(0)" ::: "memory");  // reads complete before overwrite
    __builtin_amdgcn_s_barrier();
  }

  // ---- epilogue: unscale + diag fixup + per-row (max, sumexp) base-2 partials ----
  const float ws2 = wp[0] * LOG2E;
  const float b2  = bp[0] * LOG2E;
  float2* red = (float2*)smem;  // [128][2] float2 = 2KB, safe after final barrier

#pragma unroll
  for (int i = 0; i < 4; ++i) {
#pragma unroll
    for (int rr = 0; rr < 4; ++rr) {
      const int lrow = wr * 64 + i * 16 + lg * 4 + rr;  // 0..127
      const int R = rowbase + lrow;
      const int n = R / M_UTT;
      float l2[4];
#pragma unroll
      for (int j = 0; j < 4; ++j) {
        float sim = acc[i][j][rr] * INV_SS;
        const int gc = colbase + wc * 64 + j * 16 + l16;
        if (gc == n) {
          sim = (40.f * sim - 1.f) * (1.f / 39.f);  // exclusive centroid; ||xn|| = 1
          picked2[R] = fmaf(ws2, sim, b2);
        }
        l2[j] = fmaf(ws2, sim, b2);
      }
      float mx = fmaxf(fmaxf(l2[0], l2[1]), fmaxf(l2[2], l2[3]));
#pragma unroll
      for (int d = 1; d < 16; d <<= 1) mx = fmaxf(mx, __shfl_xor(mx, d, 64));
      float s = exp2f(l2[0] - mx) + exp2f(l2[1] - mx) +
                exp2f(l2[2] - mx) + exp2f(l2[3] - mx);
#pragma unroll
      for (int d = 1; d < 16; d <<= 1) s += __shfl_xor(s, d, 64);
      if (l16 == 0) red[lrow * 2 + wc] = make_float2(mx, s);
    }
  }
  __syncthreads();
  if (tid < 128) {
    const float2 p0 = red[tid * 2 + 0];
    const float2 p1 = red[tid * 2 + 1];
    const float m2 = fmaxf(p0.x, p1.x);
    const float ss = p0.y * exp2f(p0.x - m2) + p1.y * exp2f(p1.x - m2);
    ppart[(size_t)(rowbase + tid) * 8 + cb] = make_float2(m2, ss);
  }
}

// ---------------- Kernel 3: combine 8 col-block partials -> row loss ----------------
__global__ __launch_bounds__(256) void k_combine(const float2* __restrict__ pp,
                                                 const float* __restrict__ picked2,
                                                 float* __restrict__ rowloss) {
  const int R = blockIdx.x * 256 + threadIdx.x;
  const float2* p = pp + (size_t)R * 8;
  float2 v[8];
#pragma unroll
  for (int j = 0; j < 8; ++j) v[j] = p[j];
  float m2 = v[0].x;
#pragma unroll
  for (int j = 1; j < 8; ++j) m2 = fmaxf(m2, v[j].x);
  float s = 0.f;
#pragma unroll
  for (int j = 0; j < 8; ++j) s += v[j].y * exp2f(v[j].x - m2);
  const float lse2 = m2 + log2f(s);
  rowloss[R] = (lse2 - picked2[R]) * LN2;
}

// ---------------- Kernel 4: mean over all 40960 rows ----------------
__global__ __launch_bounds__(512) void k_reduce(const float* __restrict__ rowloss,
                                                float* __restrict__ out) {
  const int t = threadIdx.x;
  double s = 0.0;
  for (int i = t; i < NROWS; i += 512) s += (double)rowloss[i];
  __shared__ double sm[512];
  sm[t] = s;
  __syncthreads();
  for (int off = 256; off > 0; off >>= 1) {
    if (t < off) sm[t] += sm[t + off];
    __syncthreads();
  }
  if (t == 0) out[0] = (float)(sm[0] / (double)NROWS);
}

extern "C" void kernel_launch(void* const* d_in, const int* in_sizes, int n_in,
                              void* d_out, int out_size, void* d_ws, size_t ws_size,
                              hipStream_t stream) {
  const float* x = (const float*)d_in[0];
  const float* w = (const float*)d_in[1];
  const float* b = (const float*)d_in[2];
  char* ws = (char*)d_ws;
  size_t off = 0;
  unsigned char* xn = (unsigned char*)(ws + off); off += (size_t)NROWS * D_FEAT;
  unsigned char* cc = (unsigned char*)(ws + off); off += (size_t)N_SPK * D_FEAT;
  off = (off + 255) & ~(size_t)255;
  float2* ppart      = (float2*)(ws + off);        off += (size_t)NROWS * 8 * sizeof(float2);
  float* picked2     = (float*)(ws + off);         off += (size_t)NROWS * sizeof(float);
  float* rowloss     = (float*)(ws + off);         off += (size_t)NROWS * sizeof(float);
  float* out = (float*)d_out;

  k_norm_cent<<<N_SPK, 256, 0, stream>>>(x, xn, cc);
  k_gemm_part<<<(NROWS / BM) * (N_SPK / BN), 256, 0, stream>>>(xn, cc, w, b, ppart, picked2);
  k_combine<<<NROWS / 256, 256, 0, stream>>>(ppart, picked2, rowloss);
  k_reduce<<<1, 512, 0, stream>>>(rowloss, out);
}

// Round 8
// 114.482 us; speedup vs baseline: 1.6388x; 1.6388x over previous
//
#include <hip/hip_runtime.h>
#include <hip/hip_bf16.h>
#include <hip/hip_fp8.h>

typedef float f32x4 __attribute__((ext_vector_type(4)));
typedef long long i64;
typedef i64 i64x2 __attribute__((ext_vector_type(2)));

#define N_SPK 1024
#define M_UTT 40
#define D_FEAT 768
#define NROWS (N_SPK * M_UTT)
#define LOG2E 1.44269504088896340736f
#define LN2   0.69314718055994530942f

#define BM 128
#define BN 128
#define BKB 64             // fp8 elems (=bytes) per K-tile
#define KT (D_FEAT / BKB)  // 12
#define ROWB 768           // bytes per fp8 source row

// xn stored *8, cc stored *8  ->  acc = 64 * sim
#define INV_SS (1.0f / 64.0f)
#define SCL 8.0f

__device__ __forceinline__ unsigned char to_fp8(float v) {
  __hip_fp8_e4m3 t(v);
  return (unsigned char)t.__x;
}

// Feature permutation (applied identically to xn and cc; dot product invariant):
// within each 64-byte k-group, 16B slot m = orig k {8m..8m+7} ++ {32+8m..32+8m+7},
// so ONE ds_read_b128 at slot lg yields both MFMA k-substeps (lo = sub0, hi = sub1).
// stored_j(j) = ((j>>3)&3)*16 + (j&7) + ((j>>5)<<3)

// ---------------- Kernel 1: fused L2-normalize + inclusive centroid (fp8, x8, permuted) ----------------
__global__ __launch_bounds__(256) void k_norm_cent(const float* __restrict__ x,
                                                   unsigned char* __restrict__ xn,
                                                   unsigned char* __restrict__ cc) {
  const int n = blockIdx.x, t = threadIdx.x;
  const float* xb = x + (size_t)n * (M_UTT * D_FEAT);
  unsigned char* ob = xn + (size_t)n * (M_UTT * D_FEAT);
  const int lane = t & 63, wv = t >> 6;
  // permuted store offset for k = t (+256, +512 share the same j = t&63)
  const int j  = t & 63;
  const int pj = ((j >> 3) & 3) * 16 + (j & 7) + ((j >> 5) << 3);
  const int s0 = (t & ~63) + pj;
  __shared__ float wsum[2][2][4];  // [parity][row-in-pair][wave]
  float c0 = 0.f, c1 = 0.f, c2 = 0.f;
  for (int m = 0; m < M_UTT; m += 2) {
    const int p = (m >> 1) & 1;
    const float* r0 = xb + (size_t)m * D_FEAT;
    const float* r1 = r0 + D_FEAT;
    float a0 = r0[t], a1 = r0[t + 256], a2 = r0[t + 512];
    float b0 = r1[t], b1 = r1[t + 256], b2 = r1[t + 512];
    float sq0 = a0 * a0 + a1 * a1 + a2 * a2;
    float sq1 = b0 * b0 + b1 * b1 + b2 * b2;
#pragma unroll
    for (int d = 1; d < 64; d <<= 1) {
      sq0 += __shfl_xor(sq0, d, 64);
      sq1 += __shfl_xor(sq1, d, 64);
    }
    if (lane == 0) { wsum[p][0][wv] = sq0; wsum[p][1][wv] = sq1; }
    __syncthreads();  // parity double-buffer: slot p reused 2 barriers later -> safe
    const float t0 = wsum[p][0][0] + wsum[p][0][1] + wsum[p][0][2] + wsum[p][0][3];
    const float t1 = wsum[p][1][0] + wsum[p][1][1] + wsum[p][1][2] + wsum[p][1][3];
    const float i0 = 1.0f / fmaxf(sqrtf(t0), 1e-12f);
    const float i1 = 1.0f / fmaxf(sqrtf(t1), 1e-12f);
    a0 *= i0; a1 *= i0; a2 *= i0;
    b0 *= i1; b1 *= i1; b2 *= i1;
    unsigned char* o0 = ob + (size_t)m * D_FEAT;
    unsigned char* o1 = o0 + D_FEAT;
    o0[s0] = to_fp8(a0 * SCL); o0[s0 + 256] = to_fp8(a1 * SCL); o0[s0 + 512] = to_fp8(a2 * SCL);
    o1[s0] = to_fp8(b0 * SCL); o1[s0 + 256] = to_fp8(b1 * SCL); o1[s0 + 512] = to_fp8(b2 * SCL);
    c0 += a0 + b0; c1 += a1 + b1; c2 += a2 + b2;
  }
  unsigned char* co = cc + (size_t)n * D_FEAT;
  co[s0]       = to_fp8(c0 * (SCL / M_UTT));
  co[s0 + 256] = to_fp8(c1 * (SCL / M_UTT));
  co[s0 + 512] = to_fp8(c2 * (SCL / M_UTT));
}

// ---------------- Kernel 2: 128x128 fp8 GEMM, K=64/tile, 4 blocks/CU, counted vmcnt ----------------
// 256 thr = 4 waves (2x2 of 64x64; 4x4 frags of 16x16x32 fp8; 32 MFMA per K-tile).
// LDS 32KB dbuf (16KB/tile): 64B src rows pair-packed into 128B LDS rows, XOR swizzle
// physical_inner = logical ^ ((R&7)<<4). Frag read = ONE ds_read_b128 per (frag,row)
// at slot lg (permuted k-layout packs both substeps) -- same wave pattern as the
// verified 0-conflict bf16 round. Loop: stage k+1 -> vmcnt(4) -> barrier ->
// 8x ds_read_b128 + 32 MFMA -> lgkmcnt(0) -> barrier. Never vmcnt(0) mid-loop.
// launch_bounds(256,4): reg cap 128/thread >= 64 AGPR acc + ~50 VGPR (no spill;
// (256,5)'s cap of ~102 caused the R7 scratch-spill regression).
#define GLD(g, l) __builtin_amdgcn_global_load_lds( \
    (const __attribute__((address_space(1))) unsigned int*)(g), \
    (__attribute__((address_space(3))) unsigned int*)(l), 16, 0, 0)

__global__ __launch_bounds__(256, 4) void k_gemm_part(
    const unsigned char* __restrict__ XN, const unsigned char* __restrict__ CC,
    const float* __restrict__ wp, const float* __restrict__ bp,
    float2* __restrict__ ppart, float* __restrict__ picked2) {

  __shared__ __align__(16) char smem[32768];

  const int tid  = threadIdx.x;
  const int wave = tid >> 6, lane = tid & 63;
  const int l16  = lane & 15, lg = lane >> 4;
  const int wr   = wave >> 1, wc = wave & 1;

  // XCD swizzle: 2560 = 8 XCD x 320; a row-tile's 8 col-blocks share one XCD's L2
  const int bid = blockIdx.x;
  const int xcd = bid & 7;
  const int tt  = bid >> 3;              // 0..319
  const int rb  = xcd * 40 + (tt >> 3);  // 0..319
  const int cb  = tt & 7;                // 0..7
  const int rowbase = rb * BM;
  const int colbase = cb * BN;

  // staging source mapping (inverse of pair-packed swizzle):
  // thread t fills LDS bytes o = chunk*4096 + t*16; LDS-row R = o>>7,
  // logical_inner = (o&127) ^ ((R&7)<<4); src_row = 2R + (li>>6), src k-byte = li&63.
  const int R7   = (tid >> 3) & 7;
  const int li   = ((tid & 7) * 16) ^ (R7 << 4);
  const int row0 = 2 * (tid >> 3) + (li >> 6);   // 0..63
  const int kb   = li & 63;
  const int t16  = tid * 16;
  const unsigned char* gA = XN + (size_t)(rowbase + row0) * ROWB + kb;
  const unsigned char* gB = CC + (size_t)(colbase + row0) * ROWB + kb;

  // fragment ds_read_b128 offsets: src row r = band*64 + i*16 + l16 ->
  // LDS-row R = band*32 + i*8 + (l16>>1); logical inner = ((l16&1)<<6)|(lg<<4),
  // physical = logical ^ ((R&7)<<4)
  const int xr  = ((l16 >> 1) & 7) << 4;
  const int in0 = ((((l16 & 1) << 6) | (lg << 4)) ^ xr);
  int aoff[4], boff[4];
#pragma unroll
  for (int i = 0; i < 4; ++i) {
    aoff[i] = (wr * 32 + i * 8 + (l16 >> 1)) * 128 + in0;
    boff[i] = 8192 + (wc * 32 + i * 8 + (l16 >> 1)) * 128 + in0;
  }

  f32x4 acc[4][4];
#pragma unroll
  for (int i = 0; i < 4; ++i)
#pragma unroll
    for (int jj = 0; jj < 4; ++jj) acc[i][jj] = (f32x4){0.f, 0.f, 0.f, 0.f};

  auto STAGE = [&](int buf, int koff) {
    char* sb = smem + buf * 16384;
    GLD(gA + koff,              sb + t16);
    GLD(gA + 64 * ROWB + koff,  sb + 4096 + t16);
    GLD(gB + koff,              sb + 8192 + t16);
    GLD(gB + 64 * ROWB + koff,  sb + 12288 + t16);
  };

  STAGE(0, 0);  // prologue: tile 0

  for (int k = 0; k < KT; ++k) {
    const char* bb = smem + (k & 1) * 16384;
    if (k + 1 < KT) {
      STAGE((k + 1) & 1, (k + 1) * BKB);
      asm volatile("s_waitcnt vmcnt(4)" ::: "memory");  // tile k landed; k+1 in flight
    } else {
      asm volatile("s_waitcnt vmcnt(0)" ::: "memory");
    }
    __builtin_amdgcn_s_barrier();

    i64x2 av[4], bv[4];
#pragma unroll
    for (int i = 0; i < 4; ++i) av[i] = *(const i64x2*)(bb + aoff[i]);
#pragma unroll
    for (int jj = 0; jj < 4; ++jj) bv[jj] = *(const i64x2*)(bb + boff[jj]);
    __builtin_amdgcn_s_setprio(1);
#pragma unroll
    for (int i = 0; i < 4; ++i)
#pragma unroll
      for (int jj = 0; jj < 4; ++jj)
        acc[i][jj] = __builtin_amdgcn_mfma_f32_16x16x32_fp8_fp8(av[i][0], bv[jj][0], acc[i][jj], 0, 0, 0);
#pragma unroll
    for (int i = 0; i < 4; ++i)
#pragma unroll
      for (int jj = 0; jj < 4; ++jj)
        acc[i][jj] = __builtin_amdgcn_mfma_f32_16x16x32_fp8_fp8(av[i][1], bv[jj][1], acc[i][jj], 0, 0, 0);
    __builtin_amdgcn_s_setprio(0);
    asm volatile("s_waitcnt lgkmcnt(0)" ::: "memory");  // reads complete before overwrite
    __builtin_amdgcn_s_barrier();
  }

  // ---- epilogue: unscale + diag fixup + per-row (max, sumexp) base-2 partials ----
  const float ws2 = wp[0] * LOG2E;
  const float b2  = bp[0] * LOG2E;
  float2* red = (float2*)smem;  // [128][2] float2 = 2KB, safe after final barrier

#pragma unroll
  for (int i = 0; i < 4; ++i) {
#pragma unroll
    for (int rr = 0; rr < 4; ++rr) {
      const int lrow = wr * 64 + i * 16 + lg * 4 + rr;  // 0..127
      const int R = rowbase + lrow;
      const int n = R / M_UTT;
      float l2[4];
#pragma unroll
      for (int jj = 0; jj < 4; ++jj) {
        float sim = acc[i][jj][rr] * INV_SS;
        const int gc = colbase + wc * 64 + jj * 16 + l16;
        if (gc == n) {
          sim = (40.f * sim - 1.f) * (1.f / 39.f);  // exclusive centroid; ||xn|| = 1
          picked2[R] = fmaf(ws2, sim, b2);
        }
        l2[jj] = fmaf(ws2, sim, b2);
      }
      float mx = fmaxf(fmaxf(l2[0], l2[1]), fmaxf(l2[2], l2[3]));
#pragma unroll
      for (int d = 1; d < 16; d <<= 1) mx = fmaxf(mx, __shfl_xor(mx, d, 64));
      float s = exp2f(l2[0] - mx) + exp2f(l2[1] - mx) +
                exp2f(l2[2] - mx) + exp2f(l2[3] - mx);
#pragma unroll
      for (int d = 1; d < 16; d <<= 1) s += __shfl_xor(s, d, 64);
      if (l16 == 0) red[lrow * 2 + wc] = make_float2(mx, s);
    }
  }
  __syncthreads();
  if (tid < 128) {
    const float2 p0 = red[tid * 2 + 0];
    const float2 p1 = red[tid * 2 + 1];
    const float m2 = fmaxf(p0.x, p1.x);
    const float ss = p0.y * exp2f(p0.x - m2) + p1.y * exp2f(p1.x - m2);
    ppart[(size_t)(rowbase + tid) * 8 + cb] = make_float2(m2, ss);
  }
}

// ---------------- Kernel 3: combine 8 col-block partials -> row loss ----------------
__global__ __launch_bounds__(256) void k_combine(const float2* __restrict__ pp,
                                                 const float* __restrict__ picked2,
                                                 float* __restrict__ rowloss) {
  const int R = blockIdx.x * 256 + threadIdx.x;
  const float2* p = pp + (size_t)R * 8;
  float2 v[8];
#pragma unroll
  for (int j = 0; j < 8; ++j) v[j] = p[j];
  float m2 = v[0].x;
#pragma unroll
  for (int j = 1; j < 8; ++j) m2 = fmaxf(m2, v[j].x);
  float s = 0.f;
#pragma unroll
  for (int j = 0; j < 8; ++j) s += v[j].y * exp2f(v[j].x - m2);
  const float lse2 = m2 + log2f(s);
  rowloss[R] = (lse2 - picked2[R]) * LN2;
}

// ---------------- Kernel 4: mean over all 40960 rows ----------------
__global__ __launch_bounds__(512) void k_reduce(const float* __restrict__ rowloss,
                                                float* __restrict__ out) {
  const int t = threadIdx.x;
  double s = 0.0;
  for (int i = t; i < NROWS; i += 512) s += (double)rowloss[i];
  __shared__ double sm[512];
  sm[t] = s;
  __syncthreads();
  for (int off = 256; off > 0; off >>= 1) {
    if (t < off) sm[t] += sm[t + off];
    __syncthreads();
  }
  if (t == 0) out[0] = (float)(sm[0] / (double)NROWS);
}

extern "C" void kernel_launch(void* const* d_in, const int* in_sizes, int n_in,
                              void* d_out, int out_size, void* d_ws, size_t ws_size,
                              hipStream_t stream) {
  const float* x = (const float*)d_in[0];
  const float* w = (const float*)d_in[1];
  const float* b = (const float*)d_in[2];
  char* ws = (char*)d_ws;
  size_t off = 0;
  unsigned char* xn = (unsigned char*)(ws + off); off += (size_t)NROWS * D_FEAT;
  unsigned char* cc = (unsigned char*)(ws + off); off += (size_t)N_SPK * D_FEAT;
  off = (off + 255) & ~(size_t)255;
  float2* ppart      = (float2*)(ws + off);        off += (size_t)NROWS * 8 * sizeof(float2);
  float* picked2     = (float*)(ws + off);         off += (size_t)NROWS * sizeof(float);
  float* rowloss     = (float*)(ws + off);         off += (size_t)NROWS * sizeof(float);
  float* out = (float*)d_out;

  k_norm_cent<<<N_SPK, 256, 0, stream>>>(x, xn, cc);
  k_gemm_part<<<(NROWS / BM) * (N_SPK / BN), 256, 0, stream>>>(xn, cc, w, b, ppart, picked2);
  k_combine<<<NROWS / 256, 256, 0, stream>>>(ppart, picked2, rowloss);
  k_reduce<<<1, 512, 0, stream>>>(rowloss, out);
}